// Round 1
// baseline (1835.316 us; speedup 1.0000x reference)
//
#include <hip/hip_runtime.h>
#include <cstdint>
#include <cstddef>

#define THRESH   0.5f
#define NEGPOS   3
#define VAR0     0.1f
#define VAR1     0.2f
#define MAXO     128
#define NPRI     8
#define A1_T     256

// ---------------------------------------------------------------------------
// Kernel A1: per-(batch, prior-chunk) matching.
//  - per-prior best truth (strict > keeps first o  == jnp.argmax axis=0)
//  - per-truth best prior via u64 key (iou_bits<<32 | ~p): atomicMax picks
//    max iou, ties -> smallest p (== jnp.argmax axis=1 first-occurrence)
// ---------------------------------------------------------------------------
__global__ __launch_bounds__(A1_T)
void match_kernel(const float* __restrict__ priors,
                  const float* __restrict__ targets,
                  float* __restrict__ bt_ov, int* __restrict__ bt_idx,
                  unsigned long long* __restrict__ g_bp,
                  int B, int P, int O, int chunks) {
    __shared__ float tx1[MAXO], ty1[MAXO], tx2[MAXO], ty2[MAXO], tarea[MAXO];
    const int b   = blockIdx.x / chunks;
    const int ch  = blockIdx.x % chunks;
    const int tid = threadIdx.x;

    if (tid < O) {
        const float* tr = targets + (size_t)(b * O + tid) * 5;
        float x1 = tr[0], y1 = tr[1], x2 = tr[2], y2 = tr[3];
        tx1[tid] = x1; ty1[tid] = y1; tx2[tid] = x2; ty2[tid] = y2;
        tarea[tid] = (x2 - x1) * (y2 - y1);
    }
    __syncthreads();

    float px1[NPRI], py1[NPRI], px2[NPRI], py2[NPRI], pa[NPRI], pov[NPRI];
    int   pidx[NPRI];
    const int p0 = ch * (A1_T * NPRI) + tid;
#pragma unroll
    for (int i = 0; i < NPRI; ++i) {
        int p = p0 + i * A1_T;
        pov[i] = -1.0f; pidx[i] = 0;
        px1[i] = 0.f; py1[i] = 0.f; px2[i] = 0.f; py2[i] = 0.f; pa[i] = 1.0f;
        if (p < P) {
            float4 pr = *(const float4*)(priors + (size_t)p * 4);
            px1[i] = pr.x - pr.z * 0.5f; py1[i] = pr.y - pr.w * 0.5f;
            px2[i] = pr.x + pr.z * 0.5f; py2[i] = pr.y + pr.w * 0.5f;
            pa[i]  = pr.z * pr.w;
        }
    }

    const int lane = tid & 63;
    for (int o = 0; o < O; ++o) {
        float ax1 = tx1[o], ay1 = ty1[o], ax2 = tx2[o], ay2 = ty2[o], aa = tarea[o];
        float bo = -1.0f; unsigned bp = 0u;
#pragma unroll
        for (int i = 0; i < NPRI; ++i) {
            int p = p0 + i * A1_T;
            if (p < P) {
                float lx = fmaxf(ax1, px1[i]), ly = fmaxf(ay1, py1[i]);
                float rx = fminf(ax2, px2[i]), ry = fminf(ay2, py2[i]);
                float w = fmaxf(rx - lx, 0.0f), h = fmaxf(ry - ly, 0.0f);
                float inter = w * h;
                float iou = inter / (aa + pa[i] - inter);
                if (iou > pov[i]) { pov[i] = iou; pidx[i] = o; }   // first o wins
                if (iou > bo)     { bo = iou; bp = (unsigned)p; }  // first (smallest) p wins
            }
        }
        unsigned long long key = 0ull;
        if (bo >= 0.0f)
            key = ((unsigned long long)__float_as_uint(bo) << 32) |
                  (unsigned long long)(0xFFFFFFFFu - bp);
        // wave butterfly max (valid keys are > 0)
#pragma unroll
        for (int d = 1; d < 64; d <<= 1) {
            unsigned long long other = __shfl_xor(key, d, 64);
            if (other > key) key = other;
        }
        if (lane == 0 && key != 0ull)
            atomicMax(&g_bp[(size_t)b * O + o], key);
    }

#pragma unroll
    for (int i = 0; i < NPRI; ++i) {
        int p = p0 + i * A1_T;
        if (p < P) {
            size_t off = (size_t)b * P + p;
            bt_ov[off]  = pov[i];
            bt_idx[off] = pidx[i];
        }
    }
}

// ---------------------------------------------------------------------------
// Kernel A2: forced-match override. Serial per batch => last truth wins on
// duplicate best_prior_idx (matches sequential .at[].set / torch loop).
// ---------------------------------------------------------------------------
__global__ void override_kernel(const unsigned long long* __restrict__ g_bp,
                                float* __restrict__ bt_ov, int* __restrict__ bt_idx,
                                int B, int P, int O) {
    int b = blockIdx.x * blockDim.x + threadIdx.x;
    if (b >= B) return;
    for (int o = 0; o < O; ++o) {
        unsigned long long key = g_bp[(size_t)b * O + o];
        unsigned p = 0xFFFFFFFFu - (unsigned)(key & 0xFFFFFFFFull);
        size_t off = (size_t)b * P + p;
        bt_ov[off]  = 2.0f;
        bt_idx[off] = o;
    }
}

// ---------------------------------------------------------------------------
// Kernel B: per-(b,p) conf_t, pos, ce values, loc smooth-L1 (pos only),
// per-row accumulators. Key identities (see header analysis):
//   logsumexp(combined logit) = lse_conf + LSE2(obj0,obj1)
//   negatives:  ce_c == ce_o == LSE2 - obj0   -> single mined array `mce`
// ---------------------------------------------------------------------------
__global__ __launch_bounds__(256)
void ce_kernel(const float* __restrict__ loc, const float* __restrict__ conf,
               const float* __restrict__ obj, const float* __restrict__ priors,
               const float* __restrict__ targets,
               const float* __restrict__ bt_ov, const int* __restrict__ bt_idx,
               float* __restrict__ mce, float* __restrict__ rowacc,
               int B, int P, int C, int O) {
    int t = blockIdx.x * blockDim.x + threadIdx.x;
    if (t >= B * P) return;
    int b = t / P;
    int p = t - b * P;

    float ov  = bt_ov[t];
    int   idx = bt_idx[t];
    const float* tr = targets + (size_t)(b * O + idx) * 5;
    int conf_t = (ov < THRESH) ? 0 : ((int)tr[4] + 1);

    float2 ob = *(const float2*)(obj + (size_t)t * 2);
    float m    = fmaxf(ob.x, ob.y);
    float lse2 = m + __logf(__expf(ob.x - m) + __expf(ob.y - m));

    if (conf_t == 0) {
        mce[t] = lse2 - ob.x;            // == ce_c == ce_o for negatives
        return;
    }
    mce[t] = 0.0f;                       // positives zeroed for mining

    // ce_c (positive): lse_conf + LSE2 - obj1 - conf[conf_t-1]
    const float* cr = conf + (size_t)t * C;
    float s0 = 0.f, s1 = 0.f, s2 = 0.f, s3 = 0.f;
    int c = 0;
    for (; c + 4 <= C; c += 4) {
        s0 += __expf(cr[c]); s1 += __expf(cr[c + 1]);
        s2 += __expf(cr[c + 2]); s3 += __expf(cr[c + 3]);
    }
    for (; c < C; ++c) s0 += __expf(cr[c]);
    float lsec = __logf((s0 + s1) + (s2 + s3));
    float cec  = lsec + lse2 - ob.y - cr[conf_t - 1];
    float ceo  = lse2 - ob.y;            // ce_o, target=1

    // localization smooth-L1 on encoded offsets
    float4 pr  = *(const float4*)(priors + (size_t)p * 4);
    float mx1 = tr[0], my1 = tr[1], mx2 = tr[2], my2 = tr[3];
    float gx = ((mx1 + mx2) * 0.5f - pr.x) / (VAR0 * pr.z);
    float gy = ((my1 + my2) * 0.5f - pr.y) / (VAR0 * pr.w);
    float gw = __logf((mx2 - mx1) / pr.z) / VAR1;
    float gh = __logf((my2 - my1) / pr.w) / VAR1;
    float4 ld = *(const float4*)(loc + (size_t)t * 4);
    float sl = 0.f;
    {
        float d0 = ld.x - gx, a0 = fabsf(d0); sl += (a0 < 1.f) ? 0.5f * d0 * d0 : a0 - 0.5f;
        float d1 = ld.y - gy, a1 = fabsf(d1); sl += (a1 < 1.f) ? 0.5f * d1 * d1 : a1 - 0.5f;
        float d2 = ld.z - gw, a2 = fabsf(d2); sl += (a2 < 1.f) ? 0.5f * d2 * d2 : a2 - 0.5f;
        float d3 = ld.w - gh, a3 = fabsf(d3); sl += (a3 < 1.f) ? 0.5f * d3 * d3 : a3 - 0.5f;
    }

    float* ra = rowacc + (size_t)b * 4;
    atomicAdd(ra + 0, sl);
    atomicAdd(ra + 1, cec);
    atomicAdd(ra + 2, ceo);
    atomicAdd(ra + 3, 1.0f);             // npos
}

// ---------------------------------------------------------------------------
// Kernel C: per-row radix-select top-k sum of mined losses (k = min(3*npos,
// P-1)). 8-bit digits MSB-first, 4 per-wave histogram copies (257 stride =>
// copies land in different LDS banks, cutting same-bin atomic serialization).
// Sum of top-k == sum(v > v_k) + (k - cnt_gt) * v_k  (tie-by-index sum-equal).
// Same neg sum applies to both loss_c and loss_obj (arrays identical).
// ---------------------------------------------------------------------------
__global__ __launch_bounds__(256)
void mine_kernel(const float* __restrict__ mce, const float* __restrict__ rowacc,
                 float* __restrict__ g_neg, int P) {
    const int b = blockIdx.x;
    const float* row = mce + (size_t)b * P;
    int npos = (int)rowacc[(size_t)b * 4 + 3];
    int k = NEGPOS * npos;
    if (k > P - 1) k = P - 1;
    if (k <= 0) return;

    __shared__ unsigned hist[4][257];
    __shared__ unsigned s_prefix;
    __shared__ int      s_rem;
    __shared__ float    s_ws[4];
    __shared__ int      s_wc[4];

    const int tid  = threadIdx.x;
    const int wv   = tid >> 6;
    const int lane = tid & 63;

    unsigned prefix = 0u;
    int rem = k;
    for (int shift = 24; shift >= 0; shift -= 8) {
        for (int i = tid; i < 4 * 257; i += 256) (&hist[0][0])[i] = 0u;
        __syncthreads();
        unsigned himask = (shift == 24) ? 0u : (0xFFFFFFFFu << (shift + 8));
        for (int i = tid; i < P; i += 256) {
            unsigned bits = __float_as_uint(row[i]);
            if ((bits & himask) == prefix)
                atomicAdd(&hist[wv][(bits >> shift) & 0xFFu], 1u);
        }
        __syncthreads();
        if (tid == 0) {
            int cum = 0; unsigned bin = 0;
            for (int bb = 255; bb >= 0; --bb) {
                int cnt = (int)(hist[0][bb] + hist[1][bb] + hist[2][bb] + hist[3][bb]);
                if (cum + cnt >= rem) { bin = (unsigned)bb; rem -= cum; break; }
                cum += cnt;
            }
            s_prefix = prefix | (bin << shift);
            s_rem = rem;
        }
        __syncthreads();
        prefix = s_prefix;
        rem    = s_rem;
    }

    float vk = __uint_as_float(prefix);
    float s = 0.f; int cnt = 0;
    for (int i = tid; i < P; i += 256) {
        float v = row[i];
        if (__float_as_uint(v) > prefix) { s += v; ++cnt; }
    }
#pragma unroll
    for (int d = 32; d > 0; d >>= 1) {
        s   += __shfl_down(s, d, 64);
        cnt += __shfl_down(cnt, d, 64);
    }
    if (lane == 0) { s_ws[wv] = s; s_wc[wv] = cnt; }
    __syncthreads();
    if (tid == 0) {
        float st = 0.f; int ct = 0;
        for (int w = 0; w < 4; ++w) { st += s_ws[w]; ct += s_wc[w]; }
        atomicAdd(g_neg, st + (float)(k - ct) * vk);
    }
}

// ---------------------------------------------------------------------------
// Kernel D: final combine + divide by N.
// ---------------------------------------------------------------------------
__global__ void finish_kernel(const float* __restrict__ rowacc,
                              const float* __restrict__ g_neg,
                              float* __restrict__ out, int B) {
    if (threadIdx.x == 0 && blockIdx.x == 0) {
        float locs = 0.f, cec = 0.f, ceo = 0.f, N = 0.f;
        for (int b = 0; b < B; ++b) {
            locs += rowacc[b * 4 + 0];
            cec  += rowacc[b * 4 + 1];
            ceo  += rowacc[b * 4 + 2];
            N    += rowacc[b * 4 + 3];
        }
        float neg = *g_neg;
        out[0] = locs / N;
        out[1] = (cec + neg) / N;
        out[2] = (ceo + neg) / N;
    }
}

extern "C" void kernel_launch(void* const* d_in, const int* in_sizes, int n_in,
                              void* d_out, int out_size, void* d_ws, size_t ws_size,
                              hipStream_t stream) {
    const float* loc     = (const float*)d_in[0];
    const float* conf    = (const float*)d_in[1];
    const float* obj     = (const float*)d_in[2];
    const float* priors  = (const float*)d_in[3];
    const float* targets = (const float*)d_in[4];

    const int P = in_sizes[3] / 4;
    const int B = in_sizes[0] / (4 * P);
    const int C = in_sizes[1] / (B * P);
    const int O = in_sizes[4] / (5 * B);

    char* ws = (char*)d_ws;
    size_t off = 0;
    float* rowacc = (float*)(ws + off);            off += (size_t)B * 4 * sizeof(float);
    float* g_neg  = (float*)(ws + off);            off += 16;
    off = (off + 7) & ~(size_t)7;
    unsigned long long* g_bp = (unsigned long long*)(ws + off);
    off += (size_t)B * O * sizeof(unsigned long long);
    const size_t zero_bytes = off;
    off = (off + 15) & ~(size_t)15;
    float* bt_ov  = (float*)(ws + off);            off += (size_t)B * P * sizeof(float);
    int*   bt_idx = (int*)(ws + off);              off += (size_t)B * P * sizeof(int);
    float* mce    = (float*)(ws + off);            off += (size_t)B * P * sizeof(float);

    hipMemsetAsync(d_ws, 0, zero_bytes, stream);

    const int chunks = (P + A1_T * NPRI - 1) / (A1_T * NPRI);
    match_kernel<<<B * chunks, A1_T, 0, stream>>>(priors, targets, bt_ov, bt_idx,
                                                  g_bp, B, P, O, chunks);
    override_kernel<<<(B + 63) / 64, 64, 0, stream>>>(g_bp, bt_ov, bt_idx, B, P, O);
    const int nt = B * P;
    ce_kernel<<<(nt + 255) / 256, 256, 0, stream>>>(loc, conf, obj, priors, targets,
                                                    bt_ov, bt_idx, mce, rowacc,
                                                    B, P, C, O);
    mine_kernel<<<B, 256, 0, stream>>>(mce, rowacc, g_neg, P);
    finish_kernel<<<1, 1, 0, stream>>>(rowacc, g_neg, (float*)d_out, B);
}

// Round 2
// 596.174 us; speedup vs baseline: 3.0785x; 3.0785x over previous
//
#include <hip/hip_runtime.h>
#include <cstdint>
#include <cstddef>

#define THRESH   0.5f
#define NEGPOS   3
#define VAR0     0.1f
#define VAR1     0.2f
#define MAXO     128
#define NPRI     8
#define A1_T     256
#define MINE_T   1024
#define MINE_W   (MINE_T / 64)
#define HCOPIES  8

// ---------------------------------------------------------------------------
// Kernel A1: per-(batch, prior-chunk) matching.
//  - per-prior best truth (strict > keeps first o  == jnp.argmax axis=0)
//  - per-truth best prior via u64 key (iou_bits<<32 | ~p): atomicMax picks
//    max iou, ties -> smallest p (== jnp.argmax axis=1 first-occurrence)
// ---------------------------------------------------------------------------
__global__ __launch_bounds__(A1_T)
void match_kernel(const float* __restrict__ priors,
                  const float* __restrict__ targets,
                  float* __restrict__ bt_ov, int* __restrict__ bt_idx,
                  unsigned long long* __restrict__ g_bp,
                  int B, int P, int O, int chunks) {
    __shared__ float tx1[MAXO], ty1[MAXO], tx2[MAXO], ty2[MAXO], tarea[MAXO];
    const int b   = blockIdx.x / chunks;
    const int ch  = blockIdx.x % chunks;
    const int tid = threadIdx.x;

    if (tid < O) {
        const float* tr = targets + (size_t)(b * O + tid) * 5;
        float x1 = tr[0], y1 = tr[1], x2 = tr[2], y2 = tr[3];
        tx1[tid] = x1; ty1[tid] = y1; tx2[tid] = x2; ty2[tid] = y2;
        tarea[tid] = (x2 - x1) * (y2 - y1);
    }
    __syncthreads();

    float px1[NPRI], py1[NPRI], px2[NPRI], py2[NPRI], pa[NPRI], pov[NPRI];
    int   pidx[NPRI];
    const int p0 = ch * (A1_T * NPRI) + tid;
#pragma unroll
    for (int i = 0; i < NPRI; ++i) {
        int p = p0 + i * A1_T;
        pov[i] = -1.0f; pidx[i] = 0;
        px1[i] = 0.f; py1[i] = 0.f; px2[i] = 0.f; py2[i] = 0.f; pa[i] = 1.0f;
        if (p < P) {
            float4 pr = *(const float4*)(priors + (size_t)p * 4);
            px1[i] = pr.x - pr.z * 0.5f; py1[i] = pr.y - pr.w * 0.5f;
            px2[i] = pr.x + pr.z * 0.5f; py2[i] = pr.y + pr.w * 0.5f;
            pa[i]  = pr.z * pr.w;
        }
    }

    const int lane = tid & 63;
    for (int o = 0; o < O; ++o) {
        float ax1 = tx1[o], ay1 = ty1[o], ax2 = tx2[o], ay2 = ty2[o], aa = tarea[o];
        float bo = -1.0f; unsigned bp = 0u;
#pragma unroll
        for (int i = 0; i < NPRI; ++i) {
            int p = p0 + i * A1_T;
            if (p < P) {
                float lx = fmaxf(ax1, px1[i]), ly = fmaxf(ay1, py1[i]);
                float rx = fminf(ax2, px2[i]), ry = fminf(ay2, py2[i]);
                float w = fmaxf(rx - lx, 0.0f), h = fmaxf(ry - ly, 0.0f);
                float inter = w * h;
                float iou = inter / (aa + pa[i] - inter);
                if (iou > pov[i]) { pov[i] = iou; pidx[i] = o; }   // first o wins
                if (iou > bo)     { bo = iou; bp = (unsigned)p; }  // first (smallest) p wins
            }
        }
        unsigned long long key = 0ull;
        if (bo >= 0.0f)
            key = ((unsigned long long)__float_as_uint(bo) << 32) |
                  (unsigned long long)(0xFFFFFFFFu - bp);
        // wave butterfly max (valid keys are > 0)
#pragma unroll
        for (int d = 1; d < 64; d <<= 1) {
            unsigned long long other = __shfl_xor(key, d, 64);
            if (other > key) key = other;
        }
        if (lane == 0 && key != 0ull)
            atomicMax(&g_bp[(size_t)b * O + o], key);
    }

#pragma unroll
    for (int i = 0; i < NPRI; ++i) {
        int p = p0 + i * A1_T;
        if (p < P) {
            size_t off = (size_t)b * P + p;
            bt_ov[off]  = pov[i];
            bt_idx[off] = pidx[i];
        }
    }
}

// ---------------------------------------------------------------------------
// Kernel A2: forced-match override. Serial per batch => last truth wins on
// duplicate best_prior_idx (matches sequential .at[].set / torch loop).
// ---------------------------------------------------------------------------
__global__ void override_kernel(const unsigned long long* __restrict__ g_bp,
                                float* __restrict__ bt_ov, int* __restrict__ bt_idx,
                                int B, int P, int O) {
    int b = blockIdx.x * blockDim.x + threadIdx.x;
    if (b >= B) return;
    for (int o = 0; o < O; ++o) {
        unsigned long long key = g_bp[(size_t)b * O + o];
        unsigned p = 0xFFFFFFFFu - (unsigned)(key & 0xFFFFFFFFull);
        size_t off = (size_t)b * P + p;
        bt_ov[off]  = 2.0f;
        bt_idx[off] = o;
    }
}

// ---------------------------------------------------------------------------
// Kernel B: per-(b,p) ce values, loc smooth-L1 (pos only), block-reduced
// row accumulators (4 atomics per BLOCK, skipped when partial == 0 — fixes
// the same-cacheline device-atomic serialization that cost 1300 us in R1).
// Grid: (ceil(P/256), B) so each block stays inside one batch row.
// Identities: logsumexp(combined logit) = lse_conf + LSE2(obj0,obj1);
// negatives: ce_c == ce_o == LSE2 - obj0  -> single mined array `mce`.
// pos <=> ov >= THRESH (labels >= 0 so conf_t >= 1 whenever matched).
// ---------------------------------------------------------------------------
__global__ __launch_bounds__(256)
void ce_kernel(const float* __restrict__ loc, const float* __restrict__ conf,
               const float* __restrict__ obj, const float* __restrict__ priors,
               const float* __restrict__ targets,
               const float* __restrict__ bt_ov, const int* __restrict__ bt_idx,
               float* __restrict__ mce, float* __restrict__ rowacc,
               int B, int P, int C, int O) {
    const int b = blockIdx.y;
    const int p = blockIdx.x * 256 + threadIdx.x;

    float sl = 0.f, cec = 0.f, ceo = 0.f, cntp = 0.f;

    if (p < P) {
        const size_t t = (size_t)b * P + p;
        float ov = bt_ov[t];
        float2 ob = *(const float2*)(obj + t * 2);
        float m    = fmaxf(ob.x, ob.y);
        float lse2 = m + __logf(__expf(ob.x - m) + __expf(ob.y - m));

        if (ov < THRESH) {
            mce[t] = lse2 - ob.x;        // negative: ce_c == ce_o, mined once
        } else {
            mce[t] = 0.0f;               // positive: zeroed for mining
            cntp = 1.0f;
            int idx = bt_idx[t];
            const float* tr = targets + (size_t)(b * O + idx) * 5;
            int conf_t = (int)tr[4] + 1;

            // ce_c: lse_conf + LSE2 - obj1 - conf[conf_t-1]
            const float* cr = conf + t * C;
            float s0 = 0.f, s1 = 0.f, s2 = 0.f, s3 = 0.f;
            int c = 0;
            for (; c + 4 <= C; c += 4) {
                s0 += __expf(cr[c]);     s1 += __expf(cr[c + 1]);
                s2 += __expf(cr[c + 2]); s3 += __expf(cr[c + 3]);
            }
            for (; c < C; ++c) s0 += __expf(cr[c]);
            float lsec = __logf((s0 + s1) + (s2 + s3));
            cec = lsec + lse2 - ob.y - cr[conf_t - 1];
            ceo = lse2 - ob.y;           // ce_o, target = 1

            // localization smooth-L1 on encoded offsets
            float4 pr = *(const float4*)(priors + (size_t)p * 4);
            float mx1 = tr[0], my1 = tr[1], mx2 = tr[2], my2 = tr[3];
            float gx = ((mx1 + mx2) * 0.5f - pr.x) / (VAR0 * pr.z);
            float gy = ((my1 + my2) * 0.5f - pr.y) / (VAR0 * pr.w);
            float gw = __logf((mx2 - mx1) / pr.z) / VAR1;
            float gh = __logf((my2 - my1) / pr.w) / VAR1;
            float4 ld = *(const float4*)(loc + t * 4);
            float d0 = ld.x - gx, a0 = fabsf(d0); sl += (a0 < 1.f) ? 0.5f * d0 * d0 : a0 - 0.5f;
            float d1 = ld.y - gy, a1 = fabsf(d1); sl += (a1 < 1.f) ? 0.5f * d1 * d1 : a1 - 0.5f;
            float d2 = ld.z - gw, a2 = fabsf(d2); sl += (a2 < 1.f) ? 0.5f * d2 * d2 : a2 - 0.5f;
            float d3 = ld.w - gh, a3 = fabsf(d3); sl += (a3 < 1.f) ? 0.5f * d3 * d3 : a3 - 0.5f;
        }
    }

    // block reduction: wave shuffle -> LDS -> 4 atomics per block (max)
    __shared__ float red[4][4];
#pragma unroll
    for (int d = 32; d > 0; d >>= 1) {
        sl   += __shfl_down(sl,   d, 64);
        cec  += __shfl_down(cec,  d, 64);
        ceo  += __shfl_down(ceo,  d, 64);
        cntp += __shfl_down(cntp, d, 64);
    }
    const int wv = threadIdx.x >> 6, lane = threadIdx.x & 63;
    if (lane == 0) { red[wv][0] = sl; red[wv][1] = cec; red[wv][2] = ceo; red[wv][3] = cntp; }
    __syncthreads();
    if (threadIdx.x < 4) {
        float v = red[0][threadIdx.x] + red[1][threadIdx.x] +
                  red[2][threadIdx.x] + red[3][threadIdx.x];
        if (v != 0.0f)
            atomicAdd(rowacc + (size_t)b * 4 + threadIdx.x, v);
    }
}

// ---------------------------------------------------------------------------
// Kernel C: per-row radix-select top-k sum of mined losses (k = min(3*npos,
// P-1)). 8-bit digits MSB-first, 8 per-wave-pair histogram copies.
// Sum of top-k == sum(v > v_k) + (k - cnt_gt) * v_k  (tie-by-index sum-equal).
// Same neg sum applies to both loss_c and loss_obj (arrays identical).
// ---------------------------------------------------------------------------
__global__ __launch_bounds__(MINE_T)
void mine_kernel(const float* __restrict__ mce, const float* __restrict__ rowacc,
                 float* __restrict__ g_neg, int P) {
    const int b = blockIdx.x;
    const float* row = mce + (size_t)b * P;
    int npos = (int)rowacc[(size_t)b * 4 + 3];
    int k = NEGPOS * npos;
    if (k > P - 1) k = P - 1;
    if (k <= 0) return;

    __shared__ unsigned hist[HCOPIES][257];
    __shared__ unsigned s_prefix;
    __shared__ int      s_rem;
    __shared__ float    s_ws[MINE_W];
    __shared__ int      s_wc[MINE_W];

    const int tid  = threadIdx.x;
    const int wv   = tid >> 6;
    const int hc   = wv & (HCOPIES - 1);
    const int lane = tid & 63;

    unsigned prefix = 0u;
    int rem = k;
    for (int shift = 24; shift >= 0; shift -= 8) {
        for (int i = tid; i < HCOPIES * 257; i += MINE_T) (&hist[0][0])[i] = 0u;
        __syncthreads();
        unsigned himask = (shift == 24) ? 0u : (0xFFFFFFFFu << (shift + 8));
        for (int i = tid; i < P; i += MINE_T) {
            unsigned bits = __float_as_uint(row[i]);
            if ((bits & himask) == prefix)
                atomicAdd(&hist[hc][(bits >> shift) & 0xFFu], 1u);
        }
        __syncthreads();
        if (tid == 0) {
            int cum = 0; unsigned bin = 0;
            for (int bb = 255; bb >= 0; --bb) {
                int cnt = 0;
#pragma unroll
                for (int h = 0; h < HCOPIES; ++h) cnt += (int)hist[h][bb];
                if (cum + cnt >= rem) { bin = (unsigned)bb; rem -= cum; break; }
                cum += cnt;
            }
            s_prefix = prefix | (bin << shift);
            s_rem = rem;
        }
        __syncthreads();
        prefix = s_prefix;
        rem    = s_rem;
    }

    float vk = __uint_as_float(prefix);
    float s = 0.f; int cnt = 0;
    for (int i = tid; i < P; i += MINE_T) {
        float v = row[i];
        if (__float_as_uint(v) > prefix) { s += v; ++cnt; }
    }
#pragma unroll
    for (int d = 32; d > 0; d >>= 1) {
        s   += __shfl_down(s, d, 64);
        cnt += __shfl_down(cnt, d, 64);
    }
    if (lane == 0) { s_ws[wv] = s; s_wc[wv] = cnt; }
    __syncthreads();
    if (tid == 0) {
        float st = 0.f; int ct = 0;
        for (int w = 0; w < MINE_W; ++w) { st += s_ws[w]; ct += s_wc[w]; }
        atomicAdd(g_neg, st + (float)(k - ct) * vk);
    }
}

// ---------------------------------------------------------------------------
// Kernel D: final combine + divide by N.
// ---------------------------------------------------------------------------
__global__ void finish_kernel(const float* __restrict__ rowacc,
                              const float* __restrict__ g_neg,
                              float* __restrict__ out, int B) {
    if (threadIdx.x == 0 && blockIdx.x == 0) {
        float locs = 0.f, cec = 0.f, ceo = 0.f, N = 0.f;
        for (int b = 0; b < B; ++b) {
            locs += rowacc[b * 4 + 0];
            cec  += rowacc[b * 4 + 1];
            ceo  += rowacc[b * 4 + 2];
            N    += rowacc[b * 4 + 3];
        }
        float neg = *g_neg;
        out[0] = locs / N;
        out[1] = (cec + neg) / N;
        out[2] = (ceo + neg) / N;
    }
}

extern "C" void kernel_launch(void* const* d_in, const int* in_sizes, int n_in,
                              void* d_out, int out_size, void* d_ws, size_t ws_size,
                              hipStream_t stream) {
    const float* loc     = (const float*)d_in[0];
    const float* conf    = (const float*)d_in[1];
    const float* obj     = (const float*)d_in[2];
    const float* priors  = (const float*)d_in[3];
    const float* targets = (const float*)d_in[4];

    const int P = in_sizes[3] / 4;
    const int B = in_sizes[0] / (4 * P);
    const int C = in_sizes[1] / (B * P);
    const int O = in_sizes[4] / (5 * B);

    char* ws = (char*)d_ws;
    size_t off = 0;
    float* rowacc = (float*)(ws + off);            off += (size_t)B * 4 * sizeof(float);
    float* g_neg  = (float*)(ws + off);            off += 16;
    off = (off + 7) & ~(size_t)7;
    unsigned long long* g_bp = (unsigned long long*)(ws + off);
    off += (size_t)B * O * sizeof(unsigned long long);
    const size_t zero_bytes = off;
    off = (off + 15) & ~(size_t)15;
    float* bt_ov  = (float*)(ws + off);            off += (size_t)B * P * sizeof(float);
    int*   bt_idx = (int*)(ws + off);              off += (size_t)B * P * sizeof(int);
    float* mce    = (float*)(ws + off);            off += (size_t)B * P * sizeof(float);

    hipMemsetAsync(d_ws, 0, zero_bytes, stream);

    const int chunks = (P + A1_T * NPRI - 1) / (A1_T * NPRI);
    match_kernel<<<B * chunks, A1_T, 0, stream>>>(priors, targets, bt_ov, bt_idx,
                                                  g_bp, B, P, O, chunks);
    override_kernel<<<(B + 63) / 64, 64, 0, stream>>>(g_bp, bt_ov, bt_idx, B, P, O);
    dim3 ce_grid((P + 255) / 256, B);
    ce_kernel<<<ce_grid, 256, 0, stream>>>(loc, conf, obj, priors, targets,
                                           bt_ov, bt_idx, mce, rowacc,
                                           B, P, C, O);
    mine_kernel<<<B, MINE_T, 0, stream>>>(mce, rowacc, g_neg, P);
    finish_kernel<<<1, 1, 0, stream>>>(rowacc, g_neg, (float*)d_out, B);
}